// Round 3
// baseline (248.773 us; speedup 1.0000x reference)
//
#include <hip/hip_runtime.h>
#include <stdint.h>
#include <math.h>

typedef unsigned int u32;
typedef unsigned long long u64;

#define E_CNT   8192
#define N_CNT   4096
#define TOT_N   (1u << 26)     // E*E elements, one threefry eval each (partitionable)
#define OUT_K   16384          // K*E = 2*8192
#define NODE_BM_WORDS 128      // 4096 bits / 32
#define N_CHUNKS 1024          // 2^26 bits / 2^16 bits-per-chunk

// ---- workspace layout (bytes) ----
#define OFF_BAD      0x000000  // u32[4096*128]   2 MiB  bad-bitmap per node
#define OFF_CNT_DST  0x200000  // u32[4096]
#define OFF_CNT_SRC  0x204000  // u32[4096]
#define OFF_CCOUNT   0x208000  // u32[1024] chunk keep-counts
#define OFF_SCALARS  0x209000  // [0]=num_neg, [1]=done ticket, [2]=T (int threshold)
#define OFF_KEEPBM   0x210000  // u64[1<<20]     8 MiB  keep bitmap
#define ZERO_BYTES   0x209040  // zero bad..scalars (keep_bm fully overwritten)

__device__ __forceinline__ u32 rotl32(u32 x, u32 d) { return (x << d) | (x >> (32u - d)); }

// JAX threefry2x32, key = (0, 42)  (jax.random.key(42) -> data [0,42])
__device__ __forceinline__ void threefry_0_42(u32 x0, u32 x1, u32& o0, u32& o1) {
  const u32 k0 = 0u, k1 = 42u, k2 = 0x1BD11BF0u; // 0 ^ 42 ^ 0x1BD11BDA
  x0 += k0; x1 += k1;
#define TF_R(r) { x0 += x1; x1 = rotl32(x1, r); x1 ^= x0; }
  TF_R(13) TF_R(15) TF_R(26) TF_R(6)
  x0 += k1; x1 += k2 + 1u;
  TF_R(17) TF_R(29) TF_R(16) TF_R(24)
  x0 += k2; x1 += k0 + 2u;
  TF_R(13) TF_R(15) TF_R(26) TF_R(6)
  x0 += k0; x1 += k1 + 3u;
  TF_R(17) TF_R(29) TF_R(16) TF_R(24)
  x0 += k1; x1 += k2 + 4u;
  TF_R(13) TF_R(15) TF_R(26) TF_R(6)
  x0 += k2; x1 += k0 + 5u;
#undef TF_R
  o0 = x0; o1 = x1;
}

// --- K1: bad bitmap + histograms + output padding prefill (independent work fused) ---
__global__ void k_build(const int* __restrict__ src, const int* __restrict__ dst,
                        u32* __restrict__ bad, u32* __restrict__ cnt_dst,
                        u32* __restrict__ cnt_src, int* __restrict__ out) {
  int tid = blockIdx.x * 256 + threadIdx.x;   // < 8192
  if (tid < N_CNT) {
    atomicOr(&bad[(u32)tid * NODE_BM_WORDS + ((u32)tid >> 5)], 1u << (tid & 31));
  }
  u32 s = (u32)src[tid], d = (u32)dst[tid];
  atomicOr(&bad[s * NODE_BM_WORDS + (d >> 5)], 1u << (d & 31));
  atomicAdd(&cnt_dst[d], 1u);
  atomicAdd(&cnt_src[s], 1u);
  // prefill: nonzero fill_value=0 -> flat idx 0 -> (src[0], dst[0])
  int s0 = src[0], d0 = dst[0];
  out[tid] = s0;            out[tid + E_CNT] = s0;
  out[OUT_K + tid] = d0;    out[OUT_K + tid + E_CNT] = d0;
}

// --- K2: num_negatives + keep_prob + integer threshold (last-block-done fused) ---
// one wave per node row; coalesced bitmap reads; shuffle reduce
__global__ void k_rowcount(const u32* __restrict__ bad, const u32* __restrict__ cnt_dst,
                           const u32* __restrict__ cnt_src, u32* __restrict__ scal) {
  int n = blockIdx.x * 4 + (threadIdx.x >> 6);  // 1024 blocks x 4 waves -> 4096 rows
  int l = threadIdx.x & 63;
  const u32* row = bad + (u32)n * NODE_BM_WORDS;
  u32 sum = 0;
#pragma unroll
  for (int h = 0; h < 2; ++h) {
    int w = l + h * 64;
    u32 bits = row[w];
    while (bits) { int b = __ffs(bits) - 1; sum += cnt_dst[(w << 5) + b]; bits &= bits - 1; }
  }
#pragma unroll
  for (int off = 32; off > 0; off >>= 1) sum += __shfl_down(sum, off, 64);
  if (l == 0) atomicAdd(&scal[0], ((u32)E_CNT - sum) * cnt_src[n]);
  __syncthreads();  // drains vmcnt -> all 4 waves' atomics complete before ticket
  if (threadIdx.x == 0) {
    __threadfence();
    if (atomicAdd(&scal[1], 1u) == (u32)(N_CNT / 4 - 1)) {
      u32 nn = atomicAdd(&scal[0], 0u);        // coherent read
      u32 ratio = nn >> 13;                    // num_neg // E
      float kp = 2.0f / (float)ratio;          // f32(K) / f32(ratio), as JAX
      // u = m*2^-23 exact; u < kp  <=>  m < ceil(kp * 2^23)
      u32 T = (u32)ceil((double)kp * 8388608.0);
      atomicExch(&scal[2], T);
    }
  }
}

// --- K3: partitionable threefry over 2^26 elements -> keep bitmap + chunk counts
// bits[i] = o0 ^ o1 where (o0,o1) = threefry2x32(key, (0, i)) ---
__global__ void __launch_bounds__(256) k_sample(const int* __restrict__ src,
                                                const int* __restrict__ dst,
                                                const u32* __restrict__ bad,
                                                const u32* __restrict__ scal,
                                                u64* __restrict__ keep_bm,
                                                u32* __restrict__ ccount) {
  u32 i = blockIdx.x * 256u + threadIdx.x;  // < 2^26
  u32 o0, o1;
  threefry_0_42(0u, i, o0, o1);
  u32 T = scal[2];
  bool keep = ((o0 ^ o1) >> 9) < T;         // integer form of (u < keep_prob)
  if (keep) {  // rare (~2.4e-4): check m = !bad_bit(src[row], dst[col])
    u32 n = (u32)src[i >> 13]; u32 v = (u32)dst[i & 8191];
    keep = ((bad[n * NODE_BM_WORDS + (v >> 5)] >> (v & 31)) & 1u) == 0u;
  }
  u64 m = __ballot(keep);
  if ((threadIdx.x & 63) == 0) {
    keep_bm[i >> 6] = m;   // lane0: i is the wave-base index
    if (m) atomicAdd(&ccount[i >> 16], (u32)__popcll(m));
  }
}

// --- K4: ordered compaction; per-block inline scan of the 1024 chunk counts ---
__global__ void k_compact(const int* __restrict__ src, const int* __restrict__ dst,
                          const u64* __restrict__ keep_bm, const u32* __restrict__ ccount,
                          int* __restrict__ out) {
  int c = blockIdx.x;                       // chunk id, 1024 u64 words each
  int t = threadIdx.x;                      // 256 threads
  __shared__ u32 s[256];
  __shared__ u32 base_sh;

  // inline exclusive prefix of ccount[0..c-1]
  u32 v[4]; u32 sum4 = 0;
#pragma unroll
  for (int k = 0; k < 4; ++k) { v[k] = ccount[4 * t + k]; sum4 += v[k]; }
  s[t] = sum4; __syncthreads();
  for (int off = 1; off < 256; off <<= 1) {
    u32 x = (t >= off) ? s[t - off] : 0u;
    __syncthreads();
    s[t] += x;
    __syncthreads();
  }
  if (t == (c >> 2)) {
    u32 excl = s[t] - sum4;
#pragma unroll
    for (int k = 0; k < 4; ++k) if (k < (c & 3)) excl += v[k];
    base_sh = excl;
  }
  __syncthreads();
  u32 coff_c = base_sh;
  __syncthreads();  // s[] about to be reused

  // per-block ordered compaction
  const u64* words = keep_bm + (size_t)c * 1024;
  u64 w[4];
  u32 cnt = 0;
#pragma unroll
  for (int k = 0; k < 4; ++k) { w[k] = words[4 * t + k]; cnt += (u32)__popcll(w[k]); }
  s[t] = cnt; __syncthreads();
  for (int off = 1; off < 256; off <<= 1) {
    u32 x = (t >= off) ? s[t - off] : 0u;
    __syncthreads();
    s[t] += x;
    __syncthreads();
  }
  u32 rank = coff_c + s[t] - cnt;           // global rank of my first set bit
  u32 tbase = (u32)c * 65536u + (u32)t * 256u;
#pragma unroll
  for (int k = 0; k < 4; ++k) {
    u64 bits = w[k];
    while (bits) {
      int b = __ffsll((unsigned long long)bits) - 1;
      if (rank < OUT_K) {
        u32 tt = tbase + (u32)k * 64u + (u32)b;
        out[rank]         = src[tt >> 13];   // edge_src[rows]
        out[OUT_K + rank] = dst[tt & 8191];  // edge_dst[cols]
      }
      rank++;
      bits &= bits - 1;
    }
  }
}

extern "C" void kernel_launch(void* const* d_in, const int* in_sizes, int n_in,
                              void* d_out, int out_size, void* d_ws, size_t ws_size,
                              hipStream_t stream) {
  const int* src = (const int*)d_in[1];  // edge_src
  const int* dst = (const int*)d_in[2];  // edge_dst  (node_feature d_in[0] unused)
  int* out = (int*)d_out;                // [edge_src_neg(16384) | edge_dst_neg(16384)]
  char* ws = (char*)d_ws;

  u32* bad     = (u32*)(ws + OFF_BAD);
  u32* cnt_dst = (u32*)(ws + OFF_CNT_DST);
  u32* cnt_src = (u32*)(ws + OFF_CNT_SRC);
  u32* ccount  = (u32*)(ws + OFF_CCOUNT);
  u32* scal    = (u32*)(ws + OFF_SCALARS);
  u64* keep_bm = (u64*)(ws + OFF_KEEPBM);

  hipMemsetAsync(ws, 0, ZERO_BYTES, stream);
  k_build<<<E_CNT / 256, 256, 0, stream>>>(src, dst, bad, cnt_dst, cnt_src, out);
  k_rowcount<<<N_CNT / 4, 256, 0, stream>>>(bad, cnt_dst, cnt_src, scal);
  k_sample<<<TOT_N / 256, 256, 0, stream>>>(src, dst, bad, scal, keep_bm, ccount);
  k_compact<<<N_CHUNKS, 256, 0, stream>>>(src, dst, keep_bm, ccount, out);
}

// Round 4
// 191.951 us; speedup vs baseline: 1.2960x; 1.2960x over previous
//
#include <hip/hip_runtime.h>
#include <stdint.h>
#include <math.h>

typedef unsigned int u32;
typedef unsigned long long u64;

#define E_CNT   8192
#define N_CNT   4096
#define TOT_N   (1u << 26)     // E*E elements, one threefry eval each (partitionable)
#define OUT_K   16384          // K*E = 2*8192
#define NODE_BM_WORDS 128      // 4096 bits / 32
#define N_CHUNKS 1024          // 2^26 bits / 2^16 bits-per-chunk

// ---- workspace layout (bytes) ----
#define OFF_BAD      0x000000  // u32[4096*128]   2 MiB  bad-bitmap per node
#define OFF_CNT_DST  0x200000  // u32[4096]
#define OFF_CNT_SRC  0x204000  // u32[4096]
#define OFF_CCOUNT   0x208000  // u32[1024] chunk keep-counts
#define OFF_SCALARS  0x209000  // [0]=num_neg, [1]=done ticket, [2]=T (int threshold)
#define OFF_KEEPBM   0x210000  // u64[1<<20]     8 MiB  keep bitmap
#define ZERO_BYTES   0x209040  // zero bad..scalars (keep_bm fully overwritten)

// rotl as a single v_alignbit_b32: alignbit(x,x,32-d) = (x>>(32-d))|(x<<d)
__device__ __forceinline__ u32 rotl32(u32 x, u32 d) {
  return __builtin_amdgcn_alignbit(x, x, 32u - d);
}

// JAX threefry2x32, key = (0, 42)  (jax.random.key(42) -> data [0,42])
__device__ __forceinline__ void threefry_0_42(u32 x0, u32 x1, u32& o0, u32& o1) {
  const u32 k0 = 0u, k1 = 42u, k2 = 0x1BD11BF0u; // 0 ^ 42 ^ 0x1BD11BDA
  x0 += k0; x1 += k1;
#define TF_R(r) { x0 += x1; x1 = rotl32(x1, r); x1 ^= x0; }
  TF_R(13) TF_R(15) TF_R(26) TF_R(6)
  x0 += k1; x1 += k2 + 1u;
  TF_R(17) TF_R(29) TF_R(16) TF_R(24)
  x0 += k2; x1 += k0 + 2u;
  TF_R(13) TF_R(15) TF_R(26) TF_R(6)
  x0 += k0; x1 += k1 + 3u;
  TF_R(17) TF_R(29) TF_R(16) TF_R(24)
  x0 += k1; x1 += k2 + 4u;
  TF_R(13) TF_R(15) TF_R(26) TF_R(6)
  x0 += k2; x1 += k0 + 5u;
#undef TF_R
  o0 = x0; o1 = x1;
}

// --- K1: bad bitmap + histograms + output padding prefill ---
__global__ void k_build(const int* __restrict__ src, const int* __restrict__ dst,
                        u32* __restrict__ bad, u32* __restrict__ cnt_dst,
                        u32* __restrict__ cnt_src, int* __restrict__ out) {
  int tid = blockIdx.x * 256 + threadIdx.x;   // < 8192
  if (tid < N_CNT) {
    atomicOr(&bad[(u32)tid * NODE_BM_WORDS + ((u32)tid >> 5)], 1u << (tid & 31));
  }
  u32 s = (u32)src[tid], d = (u32)dst[tid];
  atomicOr(&bad[s * NODE_BM_WORDS + (d >> 5)], 1u << (d & 31));
  atomicAdd(&cnt_dst[d], 1u);
  atomicAdd(&cnt_src[s], 1u);
  // prefill: nonzero fill_value=0 -> flat idx 0 -> (src[0], dst[0])
  int s0 = src[0], d0 = dst[0];
  out[tid] = s0;            out[tid + E_CNT] = s0;
  out[OUT_K + tid] = d0;    out[OUT_K + tid + E_CNT] = d0;
}

// --- K2: num_negatives + fused keep_prob/threshold epilogue ---
// one row per wave (coalesced); block LDS reduce -> 256 atomics total
__global__ void __launch_bounds__(1024) k_rowcount(const u32* __restrict__ bad,
                                                   const u32* __restrict__ cnt_dst,
                                                   const u32* __restrict__ cnt_src,
                                                   u32* __restrict__ scal) {
  int wv = threadIdx.x >> 6, ln = threadIdx.x & 63;
  int n = blockIdx.x * 16 + wv;                 // 256 blocks x 16 waves = 4096 rows
  const u32* row = bad + (u32)n * NODE_BM_WORDS;
  u32 sum = 0;
#pragma unroll
  for (int h = 0; h < 2; ++h) {
    int w = ln + h * 64;
    u32 bits = row[w];
    while (bits) { int b = __ffs(bits) - 1; sum += cnt_dst[(w << 5) + b]; bits &= bits - 1; }
  }
#pragma unroll
  for (int off = 32; off > 0; off >>= 1) sum += __shfl_down(sum, off, 64);
  __shared__ u32 part[16];
  if (ln == 0) part[wv] = ((u32)E_CNT - sum) * cnt_src[n];
  __syncthreads();
  if (threadIdx.x == 0) {
    u32 tot = 0;
#pragma unroll
    for (int k = 0; k < 16; ++k) tot += part[k];
    atomicAdd(&scal[0], tot);
    __threadfence();
    if (atomicAdd(&scal[1], 1u) == 255u) {      // last of 256 blocks
      u32 nn = atomicAdd(&scal[0], 0u);         // coherent read
      u32 ratio = nn >> 13;                     // num_neg // E
      float kp = 2.0f / (float)ratio;           // f32(K)/f32(ratio), as JAX
      // u = m*2^-23 exact; u < kp  <=>  m < ceil(kp * 2^23)
      u32 T = (u32)ceil((double)kp * 8388608.0);
      atomicExch(&scal[2], T);
    }
  }
}

// --- K3: partitionable threefry, 4 elements/thread ---
// bits[i] = o0 ^ o1, (o0,o1) = threefry2x32(key, (0, i))
__global__ void __launch_bounds__(256) k_sample(const int* __restrict__ src,
                                                const int* __restrict__ dst,
                                                const u32* __restrict__ bad,
                                                const u32* __restrict__ scal,
                                                u64* __restrict__ keep_bm,
                                                u32* __restrict__ ccount) {
  u32 base = blockIdx.x * 1024u;                // block covers 1024 elements
  u32 wv = threadIdx.x >> 6, ln = threadIdx.x & 63;
  u32 i0 = base + wv * 256u + ln;               // wave covers 256 consecutive i
  u32 T = scal[2];
  u64 words[4];
#pragma unroll
  for (int k = 0; k < 4; ++k) {
    u32 i = i0 + (u32)k * 64u;
    u32 o0, o1;
    threefry_0_42(0u, i, o0, o1);
    bool keep = ((o0 ^ o1) >> 9) < T;           // integer form of (u < keep_prob)
    if (keep) {  // rare (~2.4e-4): m = !bad_bit(src[row], dst[col])
      u32 n = (u32)src[i >> 13]; u32 v = (u32)dst[i & 8191];
      keep = ((bad[n * NODE_BM_WORDS + (v >> 5)] >> (v & 31)) & 1u) == 0u;
    }
    words[k] = __ballot(keep);
  }
  if (ln == 0) {
    u32 widx = (base >> 6) + wv * 4u;           // multiple of 4 -> 32B aligned
    ulonglong2* p = (ulonglong2*)&keep_bm[widx];
    p[0] = make_ulonglong2(words[0], words[1]);
    p[1] = make_ulonglong2(words[2], words[3]);
    u32 c = (u32)__popcll(words[0]) + (u32)__popcll(words[1]) +
            (u32)__popcll(words[2]) + (u32)__popcll(words[3]);
    if (c) atomicAdd(&ccount[base >> 16], c);   // one chunk per 64 blocks
  }
}

// --- K4: ordered compaction; per-block inline scan of the 1024 chunk counts ---
__global__ void k_compact(const int* __restrict__ src, const int* __restrict__ dst,
                          const u64* __restrict__ keep_bm, const u32* __restrict__ ccount,
                          int* __restrict__ out) {
  int c = blockIdx.x;                       // chunk id, 1024 u64 words each
  int t = threadIdx.x;                      // 256 threads
  __shared__ u32 s[256];
  __shared__ u32 base_sh;

  // inline exclusive prefix of ccount[0..c-1]
  u32 v[4]; u32 sum4 = 0;
#pragma unroll
  for (int k = 0; k < 4; ++k) { v[k] = ccount[4 * t + k]; sum4 += v[k]; }
  s[t] = sum4; __syncthreads();
  for (int off = 1; off < 256; off <<= 1) {
    u32 x = (t >= off) ? s[t - off] : 0u;
    __syncthreads();
    s[t] += x;
    __syncthreads();
  }
  if (t == (c >> 2)) {
    u32 excl = s[t] - sum4;
#pragma unroll
    for (int k = 0; k < 4; ++k) if (k < (c & 3)) excl += v[k];
    base_sh = excl;
  }
  __syncthreads();
  u32 coff_c = base_sh;
  __syncthreads();  // s[] about to be reused

  // per-block ordered compaction
  const u64* words = keep_bm + (size_t)c * 1024;
  u64 w[4];
  u32 cnt = 0;
#pragma unroll
  for (int k = 0; k < 4; ++k) { w[k] = words[4 * t + k]; cnt += (u32)__popcll(w[k]); }
  s[t] = cnt; __syncthreads();
  for (int off = 1; off < 256; off <<= 1) {
    u32 x = (t >= off) ? s[t - off] : 0u;
    __syncthreads();
    s[t] += x;
    __syncthreads();
  }
  u32 rank = coff_c + s[t] - cnt;           // global rank of my first set bit
  u32 tbase = (u32)c * 65536u + (u32)t * 256u;
#pragma unroll
  for (int k = 0; k < 4; ++k) {
    u64 bits = w[k];
    while (bits) {
      int b = __ffsll((unsigned long long)bits) - 1;
      if (rank < OUT_K) {
        u32 tt = tbase + (u32)k * 64u + (u32)b;
        out[rank]         = src[tt >> 13];   // edge_src[rows]
        out[OUT_K + rank] = dst[tt & 8191];  // edge_dst[cols]
      }
      rank++;
      bits &= bits - 1;
    }
  }
}

extern "C" void kernel_launch(void* const* d_in, const int* in_sizes, int n_in,
                              void* d_out, int out_size, void* d_ws, size_t ws_size,
                              hipStream_t stream) {
  const int* src = (const int*)d_in[1];  // edge_src
  const int* dst = (const int*)d_in[2];  // edge_dst  (node_feature d_in[0] unused)
  int* out = (int*)d_out;                // [edge_src_neg(16384) | edge_dst_neg(16384)]
  char* ws = (char*)d_ws;

  u32* bad     = (u32*)(ws + OFF_BAD);
  u32* cnt_dst = (u32*)(ws + OFF_CNT_DST);
  u32* cnt_src = (u32*)(ws + OFF_CNT_SRC);
  u32* ccount  = (u32*)(ws + OFF_CCOUNT);
  u32* scal    = (u32*)(ws + OFF_SCALARS);
  u64* keep_bm = (u64*)(ws + OFF_KEEPBM);

  hipMemsetAsync(ws, 0, ZERO_BYTES, stream);
  k_build<<<E_CNT / 256, 256, 0, stream>>>(src, dst, bad, cnt_dst, cnt_src, out);
  k_rowcount<<<N_CNT / 16, 1024, 0, stream>>>(bad, cnt_dst, cnt_src, scal);
  k_sample<<<TOT_N / 1024, 256, 0, stream>>>(src, dst, bad, scal, keep_bm, ccount);
  k_compact<<<N_CHUNKS, 256, 0, stream>>>(src, dst, keep_bm, ccount, out);
}

// Round 5
// 189.143 us; speedup vs baseline: 1.3153x; 1.0148x over previous
//
#include <hip/hip_runtime.h>
#include <stdint.h>
#include <math.h>

typedef unsigned int u32;
typedef unsigned long long u64;

#define E_CNT   8192
#define N_CNT   4096
#define TOT_N   (1u << 26)     // E*E elements, one threefry eval each (partitionable)
#define OUT_K   16384          // K*E = 2*8192
#define NODE_BM_WORDS 128      // 4096 bits / 32
#define N_CHUNKS 1024          // 2^26 bits / 2^16 bits-per-chunk

// ---- workspace layout (bytes) ----
#define OFF_BAD      0x000000  // u32[4096*128]   2 MiB  bad-bitmap per node
#define OFF_CNT_DST  0x200000  // u32[4096]
#define OFF_CNT_SRC  0x204000  // u32[4096]
#define OFF_CCOUNT   0x208000  // u32[1024] chunk keep-counts
#define OFF_SCALARS  0x209000  // [0]=num_neg, [1]=done ticket, [2]=T9 (threshold<<9)
#define OFF_KEEPBM   0x210000  // u64[1<<20]     8 MiB  keep bitmap
#define ZERO_BYTES   0x209040  // zero bad..scalars (keep_bm fully overwritten)

// rotl as a single v_alignbit_b32: alignbit(x,x,32-d) = (x>>(32-d))|(x<<d)
__device__ __forceinline__ u32 rotl32(u32 x, u32 d) {
  return __builtin_amdgcn_alignbit(x, x, 32u - d);
}

// Two interleaved JAX threefry2x32 evals, key=(0,42), counters (0,ia),(0,ib).
// Interleaving exposes 2-way ILP inside one wave (threefry is a serial chain).
// Returns bits = o0 ^ o1 (partitionable 32-bit draw).
__device__ __forceinline__ void threefry2_0_42(u32 ia, u32 ib, u32& bits_a, u32& bits_b) {
  const u32 k1 = 42u, k2 = 0x1BD11BF0u; // 0 ^ 42 ^ 0x1BD11BDA
  u32 a0 = ia + k1, a1r;   // after initial inject: x0+=k0(0) folds, x1+=k1
  u32 b0 = ib + k1;
  // NOTE: threefry state is (x0,x1); we name x1->*0 ordering carefully below.
  // Standard: x0=counter_hi=0, x1=counter_lo=i. Initial: x0+=0, x1+=42 -> x0=0, x1=i+42.
  u32 A0 = 0u, A1 = a0;    // A0=x0, A1=x1 for chain a
  u32 B0 = 0u, B1 = b0;
#define R2(r) { A0 += A1; B0 += B1; A1 = rotl32(A1, r); B1 = rotl32(B1, r); A1 ^= A0; B1 ^= B0; }
  R2(13) R2(15) R2(26) R2(6)
  A0 += k1; B0 += k1; A1 += k2 + 1u; B1 += k2 + 1u;
  R2(17) R2(29) R2(16) R2(24)
  A0 += k2; B0 += k2; A1 += 2u; B1 += 2u;            // k0+2 = 2
  R2(13) R2(15) R2(26) R2(6)
  /* A0 += k0(0) folds */ A1 += k1 + 3u; B1 += k1 + 3u;
  R2(17) R2(29) R2(16) R2(24)
  A0 += k1; B0 += k1; A1 += k2 + 4u; B1 += k2 + 4u;
  R2(13) R2(15) R2(26) R2(6)
  A0 += k2; B0 += k2; A1 += 5u; B1 += 5u;            // k0+5 = 5
#undef R2
  bits_a = A0 ^ A1;
  bits_b = B0 ^ B1;
  (void)a1r;
}

// --- K1: bad bitmap + histograms + output padding prefill ---
__global__ void k_build(const int* __restrict__ src, const int* __restrict__ dst,
                        u32* __restrict__ bad, u32* __restrict__ cnt_dst,
                        u32* __restrict__ cnt_src, int* __restrict__ out) {
  int tid = blockIdx.x * 256 + threadIdx.x;   // < 8192
  if (tid < N_CNT) {
    atomicOr(&bad[(u32)tid * NODE_BM_WORDS + ((u32)tid >> 5)], 1u << (tid & 31));
  }
  u32 s = (u32)src[tid], d = (u32)dst[tid];
  atomicOr(&bad[s * NODE_BM_WORDS + (d >> 5)], 1u << (d & 31));
  atomicAdd(&cnt_dst[d], 1u);
  atomicAdd(&cnt_src[s], 1u);
  // prefill: nonzero fill_value=0 -> flat idx 0 -> (src[0], dst[0])
  int s0 = src[0], d0 = dst[0];
  out[tid] = s0;            out[tid + E_CNT] = s0;
  out[OUT_K + tid] = d0;    out[OUT_K + tid + E_CNT] = d0;
}

// --- K2: num_negatives + fused threshold epilogue (last-block-done) ---
// one row per wave (coalesced); block LDS reduce -> 256 atomics total
__global__ void __launch_bounds__(1024) k_rowcount(const u32* __restrict__ bad,
                                                   const u32* __restrict__ cnt_dst,
                                                   const u32* __restrict__ cnt_src,
                                                   u32* __restrict__ scal) {
  int wv = threadIdx.x >> 6, ln = threadIdx.x & 63;
  int n = blockIdx.x * 16 + wv;                 // 256 blocks x 16 waves = 4096 rows
  const u32* row = bad + (u32)n * NODE_BM_WORDS;
  u32 sum = 0;
#pragma unroll
  for (int h = 0; h < 2; ++h) {
    int w = ln + h * 64;
    u32 bits = row[w];
    while (bits) { int b = __ffs(bits) - 1; sum += cnt_dst[(w << 5) + b]; bits &= bits - 1; }
  }
#pragma unroll
  for (int off = 32; off > 0; off >>= 1) sum += __shfl_down(sum, off, 64);
  __shared__ u32 part[16];
  if (ln == 0) part[wv] = ((u32)E_CNT - sum) * cnt_src[n];
  __syncthreads();
  if (threadIdx.x == 0) {
    u32 tot = 0;
#pragma unroll
    for (int k = 0; k < 16; ++k) tot += part[k];
    atomicAdd(&scal[0], tot);
    __threadfence();
    if (atomicAdd(&scal[1], 1u) == 255u) {      // last of 256 blocks
      u32 nn = atomicAdd(&scal[0], 0u);         // coherent read
      u32 ratio = nn >> 13;                     // num_neg // E
      float kp = 2.0f / (float)ratio;           // f32(K)/f32(ratio), as JAX
      // u = m*2^-23 exact; u < kp  <=>  m < T = ceil(kp*2^23)  <=>  bits < T<<9
      u32 T = (u32)ceil((double)kp * 8388608.0);
      u32 T9 = (T >= (1u << 23)) ? 0xFFFFFFFFu : (T << 9);
      atomicExch(&scal[2], T9);
    }
  }
}

// --- K3: partitionable threefry, 8 elements/thread, 2-way interleaved chains ---
__global__ void __launch_bounds__(256) k_sample(const int* __restrict__ src,
                                                const int* __restrict__ dst,
                                                const u32* __restrict__ bad,
                                                const u32* __restrict__ scal,
                                                u64* __restrict__ keep_bm,
                                                u32* __restrict__ ccount) {
  u32 wv = threadIdx.x >> 6, ln = threadIdx.x & 63;
  u32 i0w = blockIdx.x * 2048u + wv * 512u;     // wave covers 512 consecutive i
  u32 T9 = scal[2];
  u64 words[8];
  u64 any = 0;
#pragma unroll
  for (int j = 0; j < 4; ++j) {                 // pair j -> elements k=2j, 2j+1
    u32 ia = i0w + (u32)j * 128u + ln;
    u32 ba, bb;
    threefry2_0_42(ia, ia + 64u, ba, bb);
    u64 ma = __ballot(ba < T9);
    u64 mb = __ballot(bb < T9);
    words[2 * j] = ma; words[2 * j + 1] = mb;
    any |= ma | mb;
  }
  if (any) {  // rare (~12% of waves): refine kept lanes against bad bitmap
#pragma unroll
    for (int k = 0; k < 8; ++k) {
      if (words[k]) {
        u32 i = i0w + (u32)k * 64u + ln;
        bool kp = (words[k] >> ln) & 1ull;
        if (kp) {
          u32 n = (u32)src[i >> 13]; u32 v = (u32)dst[i & 8191];
          kp = ((bad[n * NODE_BM_WORDS + (v >> 5)] >> (v & 31)) & 1u) == 0u;
        }
        words[k] = __ballot(kp);
      }
    }
  }
  if (ln == 0) {
    u32 widx = i0w >> 6;                        // multiple of 8 -> 64B aligned
    ulonglong2* p = (ulonglong2*)&keep_bm[widx];
    p[0] = make_ulonglong2(words[0], words[1]);
    p[1] = make_ulonglong2(words[2], words[3]);
    p[2] = make_ulonglong2(words[4], words[5]);
    p[3] = make_ulonglong2(words[6], words[7]);
    u32 c = 0;
#pragma unroll
    for (int k = 0; k < 8; ++k) c += (u32)__popcll(words[k]);
    if (c) atomicAdd(&ccount[i0w >> 16], c);    // chunk uniform per wave
  }
}

// --- K4: ordered compaction; per-block inline scan of the 1024 chunk counts ---
__global__ void k_compact(const int* __restrict__ src, const int* __restrict__ dst,
                          const u64* __restrict__ keep_bm, const u32* __restrict__ ccount,
                          int* __restrict__ out) {
  int c = blockIdx.x;                       // chunk id, 1024 u64 words each
  int t = threadIdx.x;                      // 256 threads
  __shared__ u32 s[256];
  __shared__ u32 base_sh;

  // inline exclusive prefix of ccount[0..c-1]
  u32 v[4]; u32 sum4 = 0;
#pragma unroll
  for (int k = 0; k < 4; ++k) { v[k] = ccount[4 * t + k]; sum4 += v[k]; }
  s[t] = sum4; __syncthreads();
  for (int off = 1; off < 256; off <<= 1) {
    u32 x = (t >= off) ? s[t - off] : 0u;
    __syncthreads();
    s[t] += x;
    __syncthreads();
  }
  if (t == (c >> 2)) {
    u32 excl = s[t] - sum4;
#pragma unroll
    for (int k = 0; k < 4; ++k) if (k < (c & 3)) excl += v[k];
    base_sh = excl;
  }
  __syncthreads();
  u32 coff_c = base_sh;
  __syncthreads();  // s[] about to be reused

  // per-block ordered compaction
  const u64* words = keep_bm + (size_t)c * 1024;
  u64 w[4];
  u32 cnt = 0;
#pragma unroll
  for (int k = 0; k < 4; ++k) { w[k] = words[4 * t + k]; cnt += (u32)__popcll(w[k]); }
  s[t] = cnt; __syncthreads();
  for (int off = 1; off < 256; off <<= 1) {
    u32 x = (t >= off) ? s[t - off] : 0u;
    __syncthreads();
    s[t] += x;
    __syncthreads();
  }
  u32 rank = coff_c + s[t] - cnt;           // global rank of my first set bit
  u32 tbase = (u32)c * 65536u + (u32)t * 256u;
#pragma unroll
  for (int k = 0; k < 4; ++k) {
    u64 bits = w[k];
    while (bits) {
      int b = __ffsll((unsigned long long)bits) - 1;
      if (rank < OUT_K) {
        u32 tt = tbase + (u32)k * 64u + (u32)b;
        out[rank]         = src[tt >> 13];   // edge_src[rows]
        out[OUT_K + rank] = dst[tt & 8191];  // edge_dst[cols]
      }
      rank++;
      bits &= bits - 1;
    }
  }
}

extern "C" void kernel_launch(void* const* d_in, const int* in_sizes, int n_in,
                              void* d_out, int out_size, void* d_ws, size_t ws_size,
                              hipStream_t stream) {
  const int* src = (const int*)d_in[1];  // edge_src
  const int* dst = (const int*)d_in[2];  // edge_dst  (node_feature d_in[0] unused)
  int* out = (int*)d_out;                // [edge_src_neg(16384) | edge_dst_neg(16384)]
  char* ws = (char*)d_ws;

  u32* bad     = (u32*)(ws + OFF_BAD);
  u32* cnt_dst = (u32*)(ws + OFF_CNT_DST);
  u32* cnt_src = (u32*)(ws + OFF_CNT_SRC);
  u32* ccount  = (u32*)(ws + OFF_CCOUNT);
  u32* scal    = (u32*)(ws + OFF_SCALARS);
  u64* keep_bm = (u64*)(ws + OFF_KEEPBM);

  hipMemsetAsync(ws, 0, ZERO_BYTES, stream);
  k_build<<<E_CNT / 256, 256, 0, stream>>>(src, dst, bad, cnt_dst, cnt_src, out);
  k_rowcount<<<N_CNT / 16, 1024, 0, stream>>>(bad, cnt_dst, cnt_src, scal);
  k_sample<<<TOT_N / 2048, 256, 0, stream>>>(src, dst, bad, scal, keep_bm, ccount);
  k_compact<<<N_CHUNKS, 256, 0, stream>>>(src, dst, keep_bm, ccount, out);
}